// Round 12
// baseline (67.502 us; speedup 1.0000x reference)
//
#include <hip/hip_runtime.h>
#include <math.h>

typedef unsigned short u16;
typedef unsigned int   u32;

using bf16x8 = __attribute__((ext_vector_type(8))) short;
using f32x4  = __attribute__((ext_vector_type(4))) float;

#define NB   64
#define NE   8
#define DIN  320
#define NP   196
#define CK   768
#define CN   768
#define NKT  24      // K-chunks of 32

#define GATE_BLOCKS  8
#define WPACK_BLOCKS 2304   // 8*48*24 chunks * 64 lanes / 256
#define APACK_BLOCKS 1024   // 64 images x 16 frag-rows

__device__ __forceinline__ u16 f2bf(float f) {
    u32 u = __builtin_bit_cast(u32, f);
    u += 0x7fffu + ((u >> 16) & 1u);
    return (u16)(u >> 16);
}

// ---------------- prep1: gate1 + B-pack + A-pack patchify ----------------
// packed chunk = 1KB: lane l holds 16B = 8 bf16 along k;
//   A chunk(b, fr, kb): row = fr*16 + (l&15), k = kb*32 + (l>>4)*8
//   B chunk(e, fnG, kb): col = fnG*16 + (l&15), k = kb*32 + (l>>4)*8
__global__ __launch_bounds__(256) void prep1_kernel(
    const float* __restrict__ x,
    const float* __restrict__ g,
    const float* __restrict__ noise,
    const float* __restrict__ w_gate,
    const float* __restrict__ w_noise,
    const float* __restrict__ w_exp,
    float* __restrict__ gCl, float* __restrict__ gSd, float* __restrict__ gNy,
    u16* __restrict__ apk,
    u16* __restrict__ wpk)
{
    __shared__ char smem[24704];    // union: gate 23KB | apack 24KB
    const int t = threadIdx.x;
    int bid = blockIdx.x;

    if (bid < GATE_BLOCKS) {
        // gate stage 1: 8 blocks x 8 images; thread=(pair,q), q sums 80 dims
        float (*sW)[NE + 1]  = (float (*)[NE + 1])smem;
        float (*sWn)[NE + 1] = sW + DIN;
        for (int i = t; i < DIN * NE; i += 256) {
            sW[i >> 3][i & 7]  = w_gate[i];
            sWn[i >> 3][i & 7] = w_noise[i];
        }
        __syncthreads();
        const int pair = t >> 2, q = t & 3;
        const int bl = pair >> 3, e = pair & 7;
        const int b = bid * 8 + bl;
        float cl = 0.f, nz = 0.f;
        const float* gr = g + b * DIN + q * 80;
        #pragma unroll 4
        for (int j = 0; j < 80; ++j) {
            float gv = gr[j];
            cl = fmaf(gv, sW[q * 80 + j][e], cl);
            nz = fmaf(gv, sWn[q * 80 + j][e], nz);
        }
        cl += __shfl_xor(cl, 1); cl += __shfl_xor(cl, 2);
        nz += __shfl_xor(nz, 1); nz += __shfl_xor(nz, 2);
        if (q == 0) {
            int p = b * NE + e;
            // jax.nn.softplus == max(x,0)+log1p(exp(-|x|))
            float sd = fmaxf(nz, 0.f) + log1pf(expf(-fabsf(nz))) + 0.01f;
            gCl[p] = cl; gSd[p] = sd;
            gNy[p] = fmaf(noise[p], sd, cl);
        }
        return;
    }
    bid -= GATE_BLOCKS;

    if (bid < WPACK_BLOCKS) {
        // B-pack: thread = (chunk, lane)
        int idx = bid * 256 + t;
        int chunk = idx >> 6, l = idx & 63;
        int e   = chunk / 1152;
        int rem = chunk % 1152;
        int fnG = rem / 24;
        int kb  = rem % 24;
        const float* src = w_exp + ((size_t)(e * CN + fnG * 16 + (l & 15))) * CK
                         + kb * 32 + (l >> 4) * 8;
        float4 f0 = *reinterpret_cast<const float4*>(src);
        float4 f1 = *reinterpret_cast<const float4*>(src + 4);
        uint4 o;
        o.x = (u32)f2bf(f0.x) | ((u32)f2bf(f0.y) << 16);
        o.y = (u32)f2bf(f0.z) | ((u32)f2bf(f0.w) << 16);
        o.z = (u32)f2bf(f1.x) | ((u32)f2bf(f1.y) << 16);
        o.w = (u32)f2bf(f1.z) | ((u32)f2bf(f1.w) << 16);
        *reinterpret_cast<uint4*>(wpk + (size_t)chunk * 512 + l * 8) = o;
        return;
    }
    bid -= WPACK_BLOCKS;

    // ---- A-pack patchify (R9/R10-verified): block = (image b, frag-row fr) ----
    {
        char* pk = smem;   // 24KB staging
        const int b  = bid >> 4;
        const int fr = bid & 15;
        #pragma unroll
        for (int s = 0; s < 3; ++s) {
            int u  = t + s * 256;            // u = (lr*3 + c)*16 + ph
            int lr = u / 48;
            int c  = (u >> 4) % 3;
            int ph = u & 15;
            int p  = fr * 16 + lr; if (p > NP - 1) p = NP - 1;  // pad rows: dup of 195
            const float* src = x + ((size_t)(b * 3 + c) * 224 + (p / 14) * 16 + ph) * 224
                                 + (p % 14) * 16;
            float4 f0 = *reinterpret_cast<const float4*>(src);
            float4 f1 = *reinterpret_cast<const float4*>(src + 4);
            float4 f2 = *reinterpret_cast<const float4*>(src + 8);
            float4 f3 = *reinterpret_cast<const float4*>(src + 12);
            uint4 o0, o1;
            o0.x = (u32)f2bf(f0.x) | ((u32)f2bf(f0.y) << 16);
            o0.y = (u32)f2bf(f0.z) | ((u32)f2bf(f0.w) << 16);
            o0.z = (u32)f2bf(f1.x) | ((u32)f2bf(f1.y) << 16);
            o0.w = (u32)f2bf(f1.z) | ((u32)f2bf(f1.w) << 16);
            o1.x = (u32)f2bf(f2.x) | ((u32)f2bf(f2.y) << 16);
            o1.y = (u32)f2bf(f2.z) | ((u32)f2bf(f2.w) << 16);
            o1.z = (u32)f2bf(f3.x) | ((u32)f2bf(f3.y) << 16);
            o1.w = (u32)f2bf(f3.z) | ((u32)f2bf(f3.w) << 16);
            // k = c*256 + ph*16 + pw -> kb = c*8 + (ph>>1), lk0 = (ph&1)*2
            u32 base = (u32)((c * 8 + (ph >> 1)) * 1024 + ((ph & 1) * 2) * 256 + lr * 16);
            *reinterpret_cast<uint4*>(pk + base)       = o0;
            *reinterpret_cast<uint4*>(pk + base + 256) = o1;
        }
        __syncthreads();
        char* dst = (char*)apk + ((size_t)(b * 16 + fr) * 24) * 1024;
        #pragma unroll
        for (int s = 0; s < 6; ++s)
            *reinterpret_cast<uint4*>(dst + t * 16 + s * 4096) =
                *reinterpret_cast<const uint4*>(pk + t * 16 + s * 4096);
    }
}

// ---------------- gate2: top-2, probs, loss, eid, expert-sorted perm ----------------
__global__ __launch_bounds__(512) void gate2_kernel(
    const float* __restrict__ gCl,
    const float* __restrict__ gSd,
    const float* __restrict__ gNy,
    int* __restrict__ eid,
    int* __restrict__ perm,
    float* __restrict__ loss_out)
{
    __shared__ float sNy[NB][NE];
    __shared__ float sProb[NB][NE];
    __shared__ int   sTop[NB];
    __shared__ float sImp[NE], sLoad[NE];
    const int t = threadIdx.x;            // 512 = one (b,e) pair each
    const int b = t >> 3, e = t & 7;
    float cl = gCl[t], sd = gSd[t], ny = gNy[t];
    sNy[b][e] = ny;
    __syncthreads();
    float v1 = -1e30f, v2 = -1e30f; int i1 = 0;
    #pragma unroll
    for (int k2 = 0; k2 < NE; ++k2) {
        float v = sNy[b][k2];
        if (v > v1) { v2 = v1; v1 = v; i1 = k2; }
        else if (v > v2) { v2 = v; }
    }
    if (e == 0) { sTop[b] = i1; eid[b] = i1; }
    // is_in: noisy > 2nd-largest (thr_in=v2); else threshold = largest (v1)
    float thr = (ny > v2) ? v2 : v1;
    float z = (cl - thr) / sd;
    sProb[b][e] = 0.5f * (1.0f + erff(z * 0.7071067811865476f));
    __syncthreads();
    if (t < NE) {
        float imp = 0.f, ld = 0.f;
        for (int i = 0; i < NB; ++i) {
            imp += (sTop[i] == t) ? 1.0f : 0.0f;
            ld  += sProb[i][t];
        }
        sImp[t] = imp; sLoad[t] = ld;
    }
    __syncthreads();
    if (t == 0) {
        float mi = 0.f, ml = 0.f;
        for (int k2 = 0; k2 < NE; ++k2) { mi += sImp[k2]; ml += sLoad[k2]; }
        mi *= (1.0f / NE); ml *= (1.0f / NE);
        float vi = 0.f, vl = 0.f;
        for (int k2 = 0; k2 < NE; ++k2) {
            float d1 = sImp[k2] - mi;  vi += d1 * d1;
            float d2 = sLoad[k2] - ml; vl += d2 * d2;
        }
        vi *= (1.0f / (NE - 1)); vl *= (1.0f / (NE - 1));  // ddof=1
        loss_out[0] = (vi / (mi * mi + 1e-10f) + vl / (ml * ml + 1e-10f)) * 0.01f;
        // expert-sorted stable permutation of images (L2 locality for B)
        int off[NE]; int s = 0;
        #pragma unroll
        for (int k2 = 0; k2 < NE; ++k2) { off[k2] = s; s += (int)sImp[k2]; }
        for (int i = 0; i < NB; ++i) perm[off[sTop[i]]++] = i;
    }
}

// ---------------- fully-packed reg-streaming expert GEMM, DEPTH-2 prefetch ----------------
// 768 blocks -> (sorted slot -> image, m-tile 0/1, n-tile 0..5); 4 waves, each
// owns a 64x64 tile. Every fragment load = ONE contiguous 1KB wave-load from
// the packed A/B chunk arrays. Register TRIPLE-buffered: iter i issues loads
// for k=i+2 and computes k=i (slack = 2 MFMA clusters > L3 latency).
__global__ __launch_bounds__(256) void gemm_kernel(
    const u16* __restrict__ apk,
    const u16* __restrict__ wpk,
    const float* __restrict__ b_exp,
    const int* __restrict__ eid,
    const int* __restrict__ perm,
    float* __restrict__ out)
{
    const int id = blockIdx.x;
    // bijective XCD swizzle: 96 consecutive virtual blocks (=8 sorted slots) per XCD
    const int v  = (id & 7) * 96 + (id >> 3);
    const int b  = perm[v / 12];
    const int rr = v % 12;
    const int mt = rr / 6;
    const int nt = rr % 6;
    const int e  = eid[b];

    const int t  = threadIdx.x;
    const int l  = t & 63;
    const int w  = t >> 6;
    const int wm = w >> 1;        // m half of 128-tile
    const int wn = w & 1;         // n half of 128-tile

    // packed chunk bases; K-step advances by 1024 B
    const char* aB[4];
    const char* bB[4];
    #pragma unroll
    for (int fm = 0; fm < 4; ++fm)
        aB[fm] = (const char*)apk
               + ((size_t)((b * 16 + mt * 8 + wm * 4 + fm) * 24)) * 1024 + l * 16;
    #pragma unroll
    for (int fn = 0; fn < 4; ++fn)
        bB[fn] = (const char*)wpk
               + ((size_t)((e * 48 + nt * 8 + wn * 4 + fn) * 24)) * 1024 + l * 16;

    f32x4 acc[4][4];
    #pragma unroll
    for (int fm = 0; fm < 4; ++fm)
        #pragma unroll
        for (int fn = 0; fn < 4; ++fn)
            acc[fm][fn] = (f32x4){0.f, 0.f, 0.f, 0.f};

    bf16x8 a0[4], b0[4], a1[4], b1[4], a2[4], b2[4];

    auto LD = [&](bf16x8 (&ra)[4], bf16x8 (&rb)[4], int k) {
        if (k > NKT - 1) k = NKT - 1;   // tail clamp: redundant loads, harmless
        #pragma unroll
        for (int f = 0; f < 4; ++f) {
            ra[f] = *reinterpret_cast<const bf16x8*>(aB[f] + k * 1024);
            rb[f] = *reinterpret_cast<const bf16x8*>(bB[f] + k * 1024);
        }
    };
    auto MM = [&](bf16x8 (&ra)[4], bf16x8 (&rb)[4]) {
        __builtin_amdgcn_s_setprio(1);
        #pragma unroll
        for (int fm = 0; fm < 4; ++fm)
            #pragma unroll
            for (int fn = 0; fn < 4; ++fn)
                acc[fm][fn] = __builtin_amdgcn_mfma_f32_16x16x32_bf16(
                    ra[fm], rb[fn], acc[fm][fn], 0, 0, 0);
        __builtin_amdgcn_s_setprio(0);
    };

    // prologue: k=0 -> buf0, k=1 -> buf1
    LD(a0, b0, 0);
    LD(a1, b1, 1);

    // steady state: iter i loads k=i+2, computes k=i  (8 groups x 3 iters = 24)
    #pragma unroll 1
    for (int gq = 0; gq < 8; ++gq) {
        const int k3 = 3 * gq;
        LD(a2, b2, k3 + 2); MM(a0, b0);
        LD(a0, b0, k3 + 3); MM(a1, b1);
        LD(a1, b1, k3 + 4); MM(a2, b2);
    }

    // ---- store: bias + eps-replace, rows < 196 only ----
    const int r4 = (l >> 4) * 4;
    #pragma unroll
    for (int fm = 0; fm < 4; ++fm) {
        int mb = mt * 128 + wm * 64 + fm * 16 + r4;
        #pragma unroll
        for (int fn = 0; fn < 4; ++fn) {
            int col = nt * 128 + wn * 64 + fn * 16 + (l & 15);
            float bias = b_exp[e * CN + col];
            #pragma unroll
            for (int q = 0; q < 4; ++q) {
                int mrow = mb + q;
                if (mrow < NP) {
                    float vv = acc[fm][fn][q] + bias;
                    if (vv == 0.0f) vv = 2.220446049250313e-16f;
                    out[((size_t)b * NP + mrow) * CN + col] = vv;
                }
            }
        }
    }
}

extern "C" void kernel_launch(void* const* d_in, const int* in_sizes, int n_in,
                              void* d_out, int out_size, void* d_ws, size_t ws_size,
                              hipStream_t stream) {
    const float* x       = (const float*)d_in[0];
    const float* g       = (const float*)d_in[1];
    const float* noise   = (const float*)d_in[2];
    const float* w_gate  = (const float*)d_in[3];
    const float* w_noise = (const float*)d_in[4];
    const float* w_exp   = (const float*)d_in[5];
    const float* b_exp   = (const float*)d_in[6];
    float* out = (float*)d_out;

    char* ws = (char*)d_ws;
    int*   eid  = (int*)ws;                     // 256 B
    int*   perm = (int*)(ws + 256);             // 256 B
    float* gCl  = (float*)(ws + 512);
    float* gSd  = (float*)(ws + 2560);
    float* gNy  = (float*)(ws + 4608);
    u16*   apk  = (u16*)(ws + 8192);                          // 64*16*24*1024 = 25.2 MB
    u16*   wpk  = (u16*)(ws + 8192 + (size_t)64 * 16 * 24 * 1024);  // 9216*1024 = 9.4 MB

    hipLaunchKernelGGL(prep1_kernel,
                       dim3(GATE_BLOCKS + WPACK_BLOCKS + APACK_BLOCKS), dim3(256), 0, stream,
                       x, g, noise, w_gate, w_noise, w_exp, gCl, gSd, gNy, apk, wpk);
    hipLaunchKernelGGL(gate2_kernel, dim3(1), dim3(512), 0, stream,
                       gCl, gSd, gNy, eid, perm, out + (size_t)NB * NP * CN);
    hipLaunchKernelGGL(gemm_kernel, dim3(768), dim3(256), 0, stream,
                       apk, wpk, b_exp, eid, perm, out);
}